// Round 11
// baseline (179.206 us; speedup 1.0000x reference)
//
#include <hip/hip_runtime.h>
#include <hip/hip_bf16.h>

// GCN: h1 = relu(Â (x W1) + b1); h2 = relu(Â (h1 W2) + b2);
// out = meanpool_by_graph(h2) @ Wf + bf
// Â = D^-1/2 (A + I) D^-1/2, deg counted on edge TARGETS + self loop.
//
// GEMMs on MFMA via split-bf16 (3× mfma_f32_16x16x32_bf16, fp32 acc).
// Hybrid operand serving: B hi/lo in 64KB swizzled LDS, A register-direct.
// TM=128, 512-thread blocks -> 4 waves/SIMD.
// GEMM epilogue pre-scales row i by dinv[i], writes SLICE-MAJOR hs[8][n][16]
// (slice = contiguous 3.2MB -> fits one XCD 4MB L2).
// k_agg: slice = blockIdx%8 (XCD round-robin), gathers L2-resident;
// csr span + offs staged in LDS. Layer-2 agg fuses mean-pool (batch sorted ->
// segmented reduction + ~3 atomicAdd-runs/block) and never writes ha:
// saves 51MB of HBM round-trip. k_final divides pooled sums and applies Wf.

#define D 128

typedef __attribute__((ext_vector_type(8))) short short8;
typedef __attribute__((ext_vector_type(4))) float f32x4;

// byte offset into a K-contiguous LDS tile with 256B rows, XOR-swizzled
__device__ __forceinline__ int swz(int row, int kbyte) {
    return row * 256 + (kbyte ^ ((row & 7) << 4));
}

// ---------- init: zero degcnt + zero pooled + weight cvt ----------
__global__ __launch_bounds__(256) void k_init(int4* __restrict__ degcnt4, int n4, int zb,
                                              int4* __restrict__ pooled4, int p4, int pb,
                                              const float* __restrict__ W1,
                                              const float* __restrict__ W2,
                                              ushort* __restrict__ h1, ushort* __restrict__ l1,
                                              ushort* __restrict__ h2, ushort* __restrict__ l2) {
    int b = blockIdx.x;
    if (b < zb) {
        int i = b * 256 + threadIdx.x;
        if (i < n4) degcnt4[i] = make_int4(0, 0, 0, 0);
        return;
    }
    if (b < zb + pb) {
        int i = (b - zb) * 256 + threadIdx.x;
        if (i < p4) pooled4[i] = make_int4(0, 0, 0, 0);
        return;
    }
    int bb = b - zb - pb;                  // 0..15
    const float* W = (bb < 8) ? W1 : W2;
    ushort* Wh = (bb < 8) ? h1 : h2;
    ushort* Wl = (bb < 8) ? l1 : l2;
    int t = (bb & 7) * 256 + threadIdx.x;  // 2048 items: 128 n-rows × 16 kchunks
    int nrow = t >> 4;
    int kc = t & 15;
    uint hw[8], lw[8];
#pragma unroll
    for (int j = 0; j < 8; ++j) {
        float f = W[(kc * 8 + j) * D + nrow];
        uint ub = __float_as_uint(f);
        uint hb = ub & 0xffff0000u;
        float r = f - __uint_as_float(hb);
        hw[j] = hb >> 16;
        lw[j] = __float_as_uint(r) >> 16;
    }
    uint4 vh = make_uint4(hw[0] | (hw[1] << 16), hw[2] | (hw[3] << 16),
                          hw[4] | (hw[5] << 16), hw[6] | (hw[7] << 16));
    uint4 vl = make_uint4(lw[0] | (lw[1] << 16), lw[2] | (lw[3] << 16),
                          lw[4] | (lw[5] << 16), lw[6] | (lw[7] << 16));
    *(uint4*)&Wh[nrow * D + kc * 8] = vh;
    *(uint4*)&Wl[nrow * D + kc * 8] = vl;
}

// ---------- degree count (4 edges/thread) ----------
__global__ void k_deg(const int* __restrict__ col, int* __restrict__ cnt, int E) {
    int e = (blockIdx.x * blockDim.x + threadIdx.x) * 4;
    if (e + 3 < E) {
        int4 c = *(const int4*)&col[e];
        atomicAdd(&cnt[c.x], 1);
        atomicAdd(&cnt[c.y], 1);
        atomicAdd(&cnt[c.z], 1);
        atomicAdd(&cnt[c.w], 1);
    } else {
        for (; e < E; ++e) atomicAdd(&cnt[col[e]], 1);
    }
}

// ---------- scan level 1: per-block (1024 elems) partial sums ----------
__global__ __launch_bounds__(256) void k_scan_partial(const int* __restrict__ cnt,
                                                      int* __restrict__ partial, int n) {
    int t = threadIdx.x;
    int base = blockIdx.x * 1024 + t * 4;
    int s = 0;
#pragma unroll
    for (int j = 0; j < 4; ++j) {
        int i = base + j;
        if (i < n) s += cnt[i];
    }
#pragma unroll
    for (int o = 32; o > 0; o >>= 1) s += __shfl_down(s, o, 64);
    __shared__ int ws[4];
    if ((t & 63) == 0) ws[t >> 6] = s;
    __syncthreads();
    if (t == 0) partial[blockIdx.x] = ws[0] + ws[1] + ws[2] + ws[3];
}

// ---------- scan level 2 (fused): block prefix from raw partials + in-block scan ----------
__global__ __launch_bounds__(256) void k_scan_final(const int* __restrict__ cnt,
                                                    const int* __restrict__ partial,
                                                    int* __restrict__ offs,
                                                    int* __restrict__ cursor,
                                                    float* __restrict__ dinv,
                                                    int n, int E) {
    int t = threadIdx.x;
    int lane = t & 63;
    int base = blockIdx.x * 1024 + t * 4;
    int v[4];
    int s = 0;
#pragma unroll
    for (int j = 0; j < 4; ++j) {
        int i = base + j;
        v[j] = (i < n) ? cnt[i] : 0;
        s += v[j];
    }
    int inc = s;
#pragma unroll
    for (int o = 1; o < 64; o <<= 1) {
        int u = __shfl_up(inc, o, 64);
        if (lane >= o) inc += u;
    }
    __shared__ int wsum[4];
    __shared__ int bpref;
    if (lane == 63) wsum[t >> 6] = inc;
    if (t == 0) {
        int run = 0;
        for (int b = 0; b < blockIdx.x; ++b) run += partial[b];
        bpref = run;
        if (blockIdx.x == 0) offs[n] = E;   // total degree = E
    }
    __syncthreads();
    int woff = 0;
    int w = t >> 6;
    for (int k = 0; k < w; ++k) woff += wsum[k];
    int excl = woff + (inc - s) + bpref;
#pragma unroll
    for (int j = 0; j < 4; ++j) {
        int i = base + j;
        if (i < n) {
            offs[i] = excl;
            cursor[i] = excl;
            dinv[i] = 1.0f / sqrtf((float)(v[j] + 1));
        }
        excl += v[j];
    }
}

// ---------- CSR fill (4 edges/thread) ----------
__global__ void k_fill(const int* __restrict__ ei, int* __restrict__ cursor,
                       int* __restrict__ csr, int E) {
    int e = (blockIdx.x * blockDim.x + threadIdx.x) * 4;
    if (e + 3 < E) {
        int4 r = *(const int4*)&ei[e];
        int4 c = *(const int4*)&ei[E + e];
        int p0 = atomicAdd(&cursor[c.x], 1);
        int p1 = atomicAdd(&cursor[c.y], 1);
        int p2 = atomicAdd(&cursor[c.z], 1);
        int p3 = atomicAdd(&cursor[c.w], 1);
        csr[p0] = r.x;
        csr[p1] = r.y;
        csr[p2] = r.z;
        csr[p3] = r.w;
    } else {
        for (; e < E; ++e) {
            int rr = ei[e], cc = ei[E + e];
            int pos = atomicAdd(&cursor[cc], 1);
            csr[pos] = rr;
        }
    }
}

// ---------- MFMA GEMM (B in swizzled LDS, A register-direct, TM=128, 8 waves) ----------
// C_sliced[nt][row][li] = (A @ B)[row][nt*16+li] * dinv[row]
// A layout: ASLICED ? hs[8][n][16] : row-major [n][128].
#define TM 128
template <bool ASLICED>
__global__ __launch_bounds__(512, 4) void k_gemm(const float* __restrict__ A,
                                                 const ushort* __restrict__ Bt_hi,
                                                 const ushort* __restrict__ Bt_lo,
                                                 const float* __restrict__ dinv,
                                                 float* __restrict__ C, int n) {
    extern __shared__ char lds[];
    char* Bh = lds;               // 32KB: 128 rows × 256B
    char* Bl = lds + 32 * 1024;   // 32KB

    int tid = threadIdx.x;
    int wave = tid >> 6, lane = tid & 63;
    int li = lane & 15, lg = lane >> 4;
    int row0 = blockIdx.x * TM;
    int grow = row0 + wave * 16 + li;
    bool valid = grow < n;

    // prologue: issue all A loads (latency overlaps B staging)
    float4 a[4][2];
#pragma unroll
    for (int ks = 0; ks < 4; ++ks) {
        int k0 = ks * 32 + lg * 8;
        if (valid) {
            const float4* p;
            if (ASLICED)
                p = (const float4*)(A + ((size_t)(k0 >> 4) * n + grow) * 16 + (k0 & 15));
            else
                p = (const float4*)(A + (size_t)grow * D + k0);
            a[ks][0] = p[0];
            a[ks][1] = p[1];
        } else {
            a[ks][0] = make_float4(0.f, 0.f, 0.f, 0.f);
            a[ks][1] = make_float4(0.f, 0.f, 0.f, 0.f);
        }
    }

    // stage B (hi+lo, 2048 items) into swizzled LDS: 4 iters @ 512 threads
#pragma unroll
    for (int it = tid; it < 2048; it += 512) {
        int r = it >> 4, kc = it & 15;
        uint4 vh = *(const uint4*)(Bt_hi + r * D + kc * 8);
        uint4 vl = *(const uint4*)(Bt_lo + r * D + kc * 8);
        *(uint4*)(Bh + swz(r, kc * 16)) = vh;
        *(uint4*)(Bl + swz(r, kc * 16)) = vl;
    }
    __syncthreads();

    // convert A to split-bf16 in registers
    short8 ah[4], al[4];
#pragma unroll
    for (int ks = 0; ks < 4; ++ks) {
        float f[8] = {a[ks][0].x, a[ks][0].y, a[ks][0].z, a[ks][0].w,
                      a[ks][1].x, a[ks][1].y, a[ks][1].z, a[ks][1].w};
#pragma unroll
        for (int j = 0; j < 8; ++j) {
            uint ub = __float_as_uint(f[j]);
            uint hb = ub & 0xffff0000u;
            float r = f[j] - __uint_as_float(hb);
            ah[ks][j] = (short)(hb >> 16);
            al[ks][j] = (short)(__float_as_uint(r) >> 16);
        }
    }

    f32x4 acc[8];
#pragma unroll
    for (int i = 0; i < 8; ++i) acc[i] = (f32x4){0.f, 0.f, 0.f, 0.f};

#pragma unroll
    for (int ks = 0; ks < 4; ++ks) {
        int kb = ks * 64 + lg * 16;
#pragma unroll
        for (int nt = 0; nt < 8; ++nt) {
            short8 bh = *(const short8*)(Bh + swz(nt * 16 + li, kb));
            short8 bl = *(const short8*)(Bl + swz(nt * 16 + li, kb));
            acc[nt] = __builtin_amdgcn_mfma_f32_16x16x32_bf16(ah[ks], bh, acc[nt], 0, 0, 0);
            acc[nt] = __builtin_amdgcn_mfma_f32_16x16x32_bf16(al[ks], bh, acc[nt], 0, 0, 0);
            acc[nt] = __builtin_amdgcn_mfma_f32_16x16x32_bf16(ah[ks], bl, acc[nt], 0, 0, 0);
        }
    }

    // C/D layout (m89-verified): col = lane&15, row = (lane>>4)*4 + reg
    int crow0 = row0 + wave * 16 + lg * 4;
#pragma unroll
    for (int j = 0; j < 4; ++j) {
        int gr = crow0 + j;
        if (gr < n) {
            float dv = dinv[gr];
#pragma unroll
            for (int nt = 0; nt < 8; ++nt)
                C[((size_t)nt * n + gr) * 16 + li] = acc[nt][j] * dv;
        }
    }
}

// ---------- aggregate + bias + relu, slice-major XCD-resident ----------
// POOL=false: writes outs slice-major (layer 1).
// POOL=true: fuses global_mean_pool numerator — per-graph segmented reduction
// in LDS (batch sorted), ~3 atomicAdd runs per block; outs never written.
#define AGG_NB 128
#define CSR_CAP 2304
template <bool POOL>
__global__ __launch_bounds__(512) void k_agg(const float* __restrict__ hs,
                                             const float* __restrict__ dinv,
                                             const int* __restrict__ offs,
                                             const int* __restrict__ csr,
                                             const float* __restrict__ bias,
                                             float* __restrict__ outs,
                                             const int* __restrict__ batch,
                                             float* __restrict__ pooled, int n) {
    __shared__ int lofs[AGG_NB + 1];
    __shared__ int lcsr[CSR_CAP];
    __shared__ f32x4 arr[POOL ? AGG_NB : 1][4];
    __shared__ int gid[POOL ? AGG_NB : 1];

    int slice = blockIdx.x & 7;
    int chunk = blockIdx.x >> 3;
    int node0 = chunk * AGG_NB;
    int nend = node0 + AGG_NB; if (nend > n) nend = n;
    int nn = nend - node0;
    if ((int)threadIdx.x <= nn) lofs[threadIdx.x] = offs[node0 + threadIdx.x];
    __syncthreads();
    int S = lofs[0];
    int span = lofs[nn] - S;
    bool uselds = (span <= CSR_CAP);
    if (uselds) {
        for (int i = threadIdx.x; i < span; i += 512) lcsr[i] = csr[S + i];
    }
    __syncthreads();

    int lnode = threadIdx.x >> 2;
    int node = node0 + lnode;
    bool act = node < n;
    int l4q = threadIdx.x & 3;
    int l4 = l4q * 4;

    const float* hbase = hs + (size_t)slice * n * 16;
    f32x4 v = (f32x4){0.f, 0.f, 0.f, 0.f};
    if (act) {
        float di = dinv[node];
        int s = lofs[lnode] - S, e = lofs[lnode + 1] - S;
        f32x4 acc = *(const f32x4*)(hbase + (size_t)node * 16 + l4);  // self term
        if (uselds) {
            int p = s;
            for (; p + 8 <= e; p += 8) {
                int r0 = lcsr[p],     r1 = lcsr[p + 1], r2 = lcsr[p + 2], r3 = lcsr[p + 3];
                int r4 = lcsr[p + 4], r5 = lcsr[p + 5], r6 = lcsr[p + 6], r7 = lcsr[p + 7];
                f32x4 h0 = *(const f32x4*)(hbase + (size_t)r0 * 16 + l4);
                f32x4 h1 = *(const f32x4*)(hbase + (size_t)r1 * 16 + l4);
                f32x4 h2 = *(const f32x4*)(hbase + (size_t)r2 * 16 + l4);
                f32x4 h3 = *(const f32x4*)(hbase + (size_t)r3 * 16 + l4);
                f32x4 h4 = *(const f32x4*)(hbase + (size_t)r4 * 16 + l4);
                f32x4 h5 = *(const f32x4*)(hbase + (size_t)r5 * 16 + l4);
                f32x4 h6 = *(const f32x4*)(hbase + (size_t)r6 * 16 + l4);
                f32x4 h7 = *(const f32x4*)(hbase + (size_t)r7 * 16 + l4);
                acc += ((h0 + h1) + (h2 + h3)) + ((h4 + h5) + (h6 + h7));
            }
            for (; p + 4 <= e; p += 4) {
                int r0 = lcsr[p], r1 = lcsr[p + 1], r2 = lcsr[p + 2], r3 = lcsr[p + 3];
                f32x4 h0 = *(const f32x4*)(hbase + (size_t)r0 * 16 + l4);
                f32x4 h1 = *(const f32x4*)(hbase + (size_t)r1 * 16 + l4);
                f32x4 h2 = *(const f32x4*)(hbase + (size_t)r2 * 16 + l4);
                f32x4 h3 = *(const f32x4*)(hbase + (size_t)r3 * 16 + l4);
                acc += (h0 + h1) + (h2 + h3);
            }
            for (; p < e; ++p)
                acc += *(const f32x4*)(hbase + (size_t)lcsr[p] * 16 + l4);
        } else {
            const int* gcsr = csr + S;
            int p = s;
            for (; p + 4 <= e; p += 4) {
                int r0 = gcsr[p], r1 = gcsr[p + 1], r2 = gcsr[p + 2], r3 = gcsr[p + 3];
                f32x4 h0 = *(const f32x4*)(hbase + (size_t)r0 * 16 + l4);
                f32x4 h1 = *(const f32x4*)(hbase + (size_t)r1 * 16 + l4);
                f32x4 h2 = *(const f32x4*)(hbase + (size_t)r2 * 16 + l4);
                f32x4 h3 = *(const f32x4*)(hbase + (size_t)r3 * 16 + l4);
                acc += (h0 + h1) + (h2 + h3);
            }
            for (; p < e; ++p)
                acc += *(const f32x4*)(hbase + (size_t)gcsr[p] * 16 + l4);
        }
        f32x4 b4 = *(const f32x4*)(bias + slice * 16 + l4);
#pragma unroll
        for (int j = 0; j < 4; ++j) v[j] = fmaxf(acc[j] * di + b4[j], 0.f);
    }

    if constexpr (!POOL) {
        if (act)
            __builtin_nontemporal_store(v, (f32x4*)(outs + ((size_t)slice * n + node) * 16 + l4));
    } else {
        arr[lnode][l4q] = v;
        if (l4q == 0) gid[lnode] = act ? batch[node] : -1;
        __syncthreads();
        // walker: first node of each graph-run sums the run (batch sorted)
        if (act && (lnode == 0 || gid[lnode] != gid[lnode - 1])) {
            int g = gid[lnode];
            f32x4 ps = (f32x4){0.f, 0.f, 0.f, 0.f};
            int j = lnode;
            while (j < nn && gid[j] == g) { ps += arr[j][l4q]; ++j; }
            float* pp = pooled + (size_t)g * D + slice * 16 + l4;
            atomicAdd(pp + 0, ps[0]);
            atomicAdd(pp + 1, ps[1]);
            atomicAdd(pp + 2, ps[2]);
            atomicAdd(pp + 3, ps[3]);
        }
    }
}

// ---------- final: pooled/cnt then @ Wf + bf ----------
__global__ __launch_bounds__(128) void k_final(const float* __restrict__ pooled,
                                               const int* __restrict__ batch, int n,
                                               const float* __restrict__ Wf,
                                               const float* __restrict__ bf,
                                               float* __restrict__ out) {
    __shared__ int sse[2];
    __shared__ float pr[D];
    int g = blockIdx.x;
    if (threadIdx.x == 0) {
        int lo = 0, hi = n;
        while (lo < hi) { int m = (lo + hi) >> 1; if (batch[m] < g) lo = m + 1; else hi = m; }
        sse[0] = lo;
    } else if (threadIdx.x == 64) {
        int lo = 0, hi = n;
        while (lo < hi) { int m = (lo + hi) >> 1; if (batch[m] < g + 1) lo = m + 1; else hi = m; }
        sse[1] = lo;
    }
    __syncthreads();
    float cnt = (float)(sse[1] - sse[0]);
    if (cnt < 1.f) cnt = 1.f;
    int d = threadIdx.x;
    pr[d] = pooled[(size_t)g * D + d] / cnt;
    __syncthreads();
    float o = bf[d];
#pragma unroll 8
    for (int k = 0; k < D; ++k) o += pr[k] * Wf[k * D + d];
    out[g * D + d] = o;
}

extern "C" void kernel_launch(void* const* d_in, const int* in_sizes, int n_in,
                              void* d_out, int out_size, void* d_ws, size_t ws_size,
                              hipStream_t stream) {
    const float* x  = (const float*)d_in[0];
    const int*   ei = (const int*)d_in[1];
    const int*   bt = (const int*)d_in[2];
    const float* W1 = (const float*)d_in[3];
    const float* b1 = (const float*)d_in[4];
    const float* W2 = (const float*)d_in[5];
    const float* b2 = (const float*)d_in[6];
    const float* Wf = (const float*)d_in[7];
    const float* bf = (const float*)d_in[8];
    float* out = (float*)d_out;

    int n = in_sizes[2];
    int E = in_sizes[1] / 2;
    int G = out_size / D;

    char* w = (char*)d_ws;
    size_t off = 0;
    auto alloc = [&](size_t bytes) -> void* {
        void* p = w + off;
        off = (off + bytes + 511) & ~(size_t)511;
        return p;
    };
    int*    degcnt = (int*)alloc((size_t)n * 4);
    int*    cursor = (int*)alloc((size_t)n * 4);
    int*    offs   = (int*)alloc((size_t)(n + 1) * 4);
    float*  dinv   = (float*)alloc((size_t)n * 4);
    int*    csr    = (int*)alloc((size_t)E * 4);
    float*  hw     = (float*)alloc((size_t)n * D * 4);   // slice-major [8][n][16]
    float*  ha     = (float*)alloc((size_t)n * D * 4);   // slice-major [8][n][16]
    float*  pooled = (float*)alloc((size_t)G * D * 4);
    int*    partial= (int*)alloc((size_t)256 * 4);
    ushort* wt1h   = (ushort*)alloc((size_t)D * D * 2);
    ushort* wt1l   = (ushort*)alloc((size_t)D * D * 2);
    ushort* wt2h   = (ushort*)alloc((size_t)D * D * 2);
    ushort* wt2l   = (ushort*)alloc((size_t)D * D * 2);

    int n4 = (n + 3) / 4;
    int zb = (n4 + 255) / 256;
    int p4 = (G * D + 3) / 4;
    int pb = (p4 + 255) / 256;
    k_init<<<zb + pb + 16, 256, 0, stream>>>((int4*)degcnt, n4, zb,
                                             (int4*)pooled, p4, pb,
                                             W1, W2, wt1h, wt1l, wt2h, wt2l);

    int e4b = (E / 4 + 255) / 256 + 1;
    int sb = (n + 1023) / 1024;
    k_deg<<<e4b, 256, 0, stream>>>(ei + E, degcnt, E);
    k_scan_partial<<<sb, 256, 0, stream>>>(degcnt, partial, n);
    k_scan_final<<<sb, 256, 0, stream>>>(degcnt, partial, offs, cursor, dinv, n, E);
    k_fill<<<e4b, 256, 0, stream>>>(ei, cursor, csr, E);

    int gb = (n + TM - 1) / TM;
    int ab = 8 * ((n + AGG_NB - 1) / AGG_NB);
    size_t lds_bytes = 64 * 1024;

    k_gemm<false><<<gb, 512, lds_bytes, stream>>>(x, wt1h, wt1l, dinv, hw, n);
    k_agg<false><<<ab, 512, 0, stream>>>(hw, dinv, offs, csr, b1, ha, bt, nullptr, n);
    k_gemm<true><<<gb, 512, lds_bytes, stream>>>(ha, wt2h, wt2l, dinv, hw, n);
    k_agg<true><<<ab, 512, 0, stream>>>(hw, dinv, offs, csr, b2, nullptr, bt, pooled, n);
    k_final<<<G, 128, 0, stream>>>(pooled, bt, n, Wf, bf, out);
}

// Round 13
// 163.215 us; speedup vs baseline: 1.0980x; 1.0980x over previous
//
#include <hip/hip_runtime.h>
#include <hip/hip_bf16.h>

// GCN: h1 = relu(Â (x W1) + b1); h2 = relu(Â (h1 W2) + b2);
// out = meanpool_by_graph(h2) @ Wf + bf
// Â = D^-1/2 (A + I) D^-1/2, deg counted on edge TARGETS + self loop.
//
// GEMMs on MFMA via split-bf16 (3× mfma_f32_16x16x32_bf16, fp32 acc).
// Hybrid operand serving: B hi/lo in 64KB swizzled LDS, A register-direct.
// TM=128, 512-thread blocks -> 4 waves/SIMD.
// GEMM epilogue pre-scales row i by dinv[i], writes SLICE-MAJOR hs[8][n][16]
// (slice = contiguous 3.2MB -> fits one XCD 4MB L2).
// k_agg: slice = blockIdx%8 (XCD round-robin), gathers L2-resident;
// csr span + offs staged in LDS. Layer-2 agg fuses mean-pool via wave-level
// segmented shfl reduce. NOTE (R12 bug): CDNA __shfl_down is ds_bpermute
// with lane addresses wrapping MOD 64 — the doubling loop needs an explicit
// (lane+o)<64 guard or top lanes absorb bottom-lane partials. Fixed here.
// ha never written (saves 51MB HBM). k_final divides pooled and applies Wf.

#define D 128

typedef __attribute__((ext_vector_type(8))) short short8;
typedef __attribute__((ext_vector_type(4))) float f32x4;

// byte offset into a K-contiguous LDS tile with 256B rows, XOR-swizzled
__device__ __forceinline__ int swz(int row, int kbyte) {
    return row * 256 + (kbyte ^ ((row & 7) << 4));
}

// ---------- init: zero degcnt + zero pooled + weight cvt ----------
__global__ __launch_bounds__(256) void k_init(int4* __restrict__ degcnt4, int n4, int zb,
                                              int4* __restrict__ pooled4, int p4, int pb,
                                              const float* __restrict__ W1,
                                              const float* __restrict__ W2,
                                              ushort* __restrict__ h1, ushort* __restrict__ l1,
                                              ushort* __restrict__ h2, ushort* __restrict__ l2) {
    int b = blockIdx.x;
    if (b < zb) {
        int i = b * 256 + threadIdx.x;
        if (i < n4) degcnt4[i] = make_int4(0, 0, 0, 0);
        return;
    }
    if (b < zb + pb) {
        int i = (b - zb) * 256 + threadIdx.x;
        if (i < p4) pooled4[i] = make_int4(0, 0, 0, 0);
        return;
    }
    int bb = b - zb - pb;                  // 0..15
    const float* W = (bb < 8) ? W1 : W2;
    ushort* Wh = (bb < 8) ? h1 : h2;
    ushort* Wl = (bb < 8) ? l1 : l2;
    int t = (bb & 7) * 256 + threadIdx.x;  // 2048 items: 128 n-rows × 16 kchunks
    int nrow = t >> 4;
    int kc = t & 15;
    uint hw[8], lw[8];
#pragma unroll
    for (int j = 0; j < 8; ++j) {
        float f = W[(kc * 8 + j) * D + nrow];
        uint ub = __float_as_uint(f);
        uint hb = ub & 0xffff0000u;
        float r = f - __uint_as_float(hb);
        hw[j] = hb >> 16;
        lw[j] = __float_as_uint(r) >> 16;
    }
    uint4 vh = make_uint4(hw[0] | (hw[1] << 16), hw[2] | (hw[3] << 16),
                          hw[4] | (hw[5] << 16), hw[6] | (hw[7] << 16));
    uint4 vl = make_uint4(lw[0] | (lw[1] << 16), lw[2] | (lw[3] << 16),
                          lw[4] | (lw[5] << 16), lw[6] | (lw[7] << 16));
    *(uint4*)&Wh[nrow * D + kc * 8] = vh;
    *(uint4*)&Wl[nrow * D + kc * 8] = vl;
}

// ---------- degree count (4 edges/thread) ----------
__global__ void k_deg(const int* __restrict__ col, int* __restrict__ cnt, int E) {
    int e = (blockIdx.x * blockDim.x + threadIdx.x) * 4;
    if (e + 3 < E) {
        int4 c = *(const int4*)&col[e];
        atomicAdd(&cnt[c.x], 1);
        atomicAdd(&cnt[c.y], 1);
        atomicAdd(&cnt[c.z], 1);
        atomicAdd(&cnt[c.w], 1);
    } else {
        for (; e < E; ++e) atomicAdd(&cnt[col[e]], 1);
    }
}

// ---------- scan level 1: per-block (1024 elems) partial sums ----------
__global__ __launch_bounds__(256) void k_scan_partial(const int* __restrict__ cnt,
                                                      int* __restrict__ partial, int n) {
    int t = threadIdx.x;
    int base = blockIdx.x * 1024 + t * 4;
    int s = 0;
#pragma unroll
    for (int j = 0; j < 4; ++j) {
        int i = base + j;
        if (i < n) s += cnt[i];
    }
#pragma unroll
    for (int o = 32; o > 0; o >>= 1) s += __shfl_down(s, o, 64);
    __shared__ int ws[4];
    if ((t & 63) == 0) ws[t >> 6] = s;
    __syncthreads();
    if (t == 0) partial[blockIdx.x] = ws[0] + ws[1] + ws[2] + ws[3];
}

// ---------- scan level 2 (fused): block prefix from raw partials + in-block scan ----------
__global__ __launch_bounds__(256) void k_scan_final(const int* __restrict__ cnt,
                                                    const int* __restrict__ partial,
                                                    int* __restrict__ offs,
                                                    int* __restrict__ cursor,
                                                    float* __restrict__ dinv,
                                                    int n, int E) {
    int t = threadIdx.x;
    int lane = t & 63;
    int base = blockIdx.x * 1024 + t * 4;
    int v[4];
    int s = 0;
#pragma unroll
    for (int j = 0; j < 4; ++j) {
        int i = base + j;
        v[j] = (i < n) ? cnt[i] : 0;
        s += v[j];
    }
    int inc = s;
#pragma unroll
    for (int o = 1; o < 64; o <<= 1) {
        int u = __shfl_up(inc, o, 64);
        if (lane >= o) inc += u;
    }
    __shared__ int wsum[4];
    __shared__ int bpref;
    if (lane == 63) wsum[t >> 6] = inc;
    if (t == 0) {
        int run = 0;
        for (int b = 0; b < blockIdx.x; ++b) run += partial[b];
        bpref = run;
        if (blockIdx.x == 0) offs[n] = E;   // total degree = E
    }
    __syncthreads();
    int woff = 0;
    int w = t >> 6;
    for (int k = 0; k < w; ++k) woff += wsum[k];
    int excl = woff + (inc - s) + bpref;
#pragma unroll
    for (int j = 0; j < 4; ++j) {
        int i = base + j;
        if (i < n) {
            offs[i] = excl;
            cursor[i] = excl;
            dinv[i] = 1.0f / sqrtf((float)(v[j] + 1));
        }
        excl += v[j];
    }
}

// ---------- CSR fill (4 edges/thread) ----------
__global__ void k_fill(const int* __restrict__ ei, int* __restrict__ cursor,
                       int* __restrict__ csr, int E) {
    int e = (blockIdx.x * blockDim.x + threadIdx.x) * 4;
    if (e + 3 < E) {
        int4 r = *(const int4*)&ei[e];
        int4 c = *(const int4*)&ei[E + e];
        int p0 = atomicAdd(&cursor[c.x], 1);
        int p1 = atomicAdd(&cursor[c.y], 1);
        int p2 = atomicAdd(&cursor[c.z], 1);
        int p3 = atomicAdd(&cursor[c.w], 1);
        csr[p0] = r.x;
        csr[p1] = r.y;
        csr[p2] = r.z;
        csr[p3] = r.w;
    } else {
        for (; e < E; ++e) {
            int rr = ei[e], cc = ei[E + e];
            int pos = atomicAdd(&cursor[cc], 1);
            csr[pos] = rr;
        }
    }
}

// ---------- MFMA GEMM (B in swizzled LDS, A register-direct, TM=128, 8 waves) ----------
// C_sliced[nt][row][li] = (A @ B)[row][nt*16+li] * dinv[row]
// A layout: ASLICED ? hs[8][n][16] : row-major [n][128].
#define TM 128
template <bool ASLICED>
__global__ __launch_bounds__(512, 4) void k_gemm(const float* __restrict__ A,
                                                 const ushort* __restrict__ Bt_hi,
                                                 const ushort* __restrict__ Bt_lo,
                                                 const float* __restrict__ dinv,
                                                 float* __restrict__ C, int n) {
    extern __shared__ char lds[];
    char* Bh = lds;               // 32KB: 128 rows × 256B
    char* Bl = lds + 32 * 1024;   // 32KB

    int tid = threadIdx.x;
    int wave = tid >> 6, lane = tid & 63;
    int li = lane & 15, lg = lane >> 4;
    int row0 = blockIdx.x * TM;
    int grow = row0 + wave * 16 + li;
    bool valid = grow < n;

    // prologue: issue all A loads (latency overlaps B staging)
    float4 a[4][2];
#pragma unroll
    for (int ks = 0; ks < 4; ++ks) {
        int k0 = ks * 32 + lg * 8;
        if (valid) {
            const float4* p;
            if (ASLICED)
                p = (const float4*)(A + ((size_t)(k0 >> 4) * n + grow) * 16 + (k0 & 15));
            else
                p = (const float4*)(A + (size_t)grow * D + k0);
            a[ks][0] = p[0];
            a[ks][1] = p[1];
        } else {
            a[ks][0] = make_float4(0.f, 0.f, 0.f, 0.f);
            a[ks][1] = make_float4(0.f, 0.f, 0.f, 0.f);
        }
    }

    // stage B (hi+lo, 2048 items) into swizzled LDS: 4 iters @ 512 threads
#pragma unroll
    for (int it = tid; it < 2048; it += 512) {
        int r = it >> 4, kc = it & 15;
        uint4 vh = *(const uint4*)(Bt_hi + r * D + kc * 8);
        uint4 vl = *(const uint4*)(Bt_lo + r * D + kc * 8);
        *(uint4*)(Bh + swz(r, kc * 16)) = vh;
        *(uint4*)(Bl + swz(r, kc * 16)) = vl;
    }
    __syncthreads();

    // convert A to split-bf16 in registers
    short8 ah[4], al[4];
#pragma unroll
    for (int ks = 0; ks < 4; ++ks) {
        float f[8] = {a[ks][0].x, a[ks][0].y, a[ks][0].z, a[ks][0].w,
                      a[ks][1].x, a[ks][1].y, a[ks][1].z, a[ks][1].w};
#pragma unroll
        for (int j = 0; j < 8; ++j) {
            uint ub = __float_as_uint(f[j]);
            uint hb = ub & 0xffff0000u;
            float r = f[j] - __uint_as_float(hb);
            ah[ks][j] = (short)(hb >> 16);
            al[ks][j] = (short)(__float_as_uint(r) >> 16);
        }
    }

    f32x4 acc[8];
#pragma unroll
    for (int i = 0; i < 8; ++i) acc[i] = (f32x4){0.f, 0.f, 0.f, 0.f};

#pragma unroll
    for (int ks = 0; ks < 4; ++ks) {
        int kb = ks * 64 + lg * 16;
#pragma unroll
        for (int nt = 0; nt < 8; ++nt) {
            short8 bh = *(const short8*)(Bh + swz(nt * 16 + li, kb));
            short8 bl = *(const short8*)(Bl + swz(nt * 16 + li, kb));
            acc[nt] = __builtin_amdgcn_mfma_f32_16x16x32_bf16(ah[ks], bh, acc[nt], 0, 0, 0);
            acc[nt] = __builtin_amdgcn_mfma_f32_16x16x32_bf16(al[ks], bh, acc[nt], 0, 0, 0);
            acc[nt] = __builtin_amdgcn_mfma_f32_16x16x32_bf16(ah[ks], bl, acc[nt], 0, 0, 0);
        }
    }

    // C/D layout (m89-verified): col = lane&15, row = (lane>>4)*4 + reg
    int crow0 = row0 + wave * 16 + lg * 4;
#pragma unroll
    for (int j = 0; j < 4; ++j) {
        int gr = crow0 + j;
        if (gr < n) {
            float dv = dinv[gr];
#pragma unroll
            for (int nt = 0; nt < 8; ++nt)
                C[((size_t)nt * n + gr) * 16 + li] = acc[nt][j] * dv;
        }
    }
}

// ---------- aggregate + bias + relu, slice-major XCD-resident ----------
// POOL=false: writes outs slice-major (layer 1).
// POOL=true: fuses mean-pool numerator via wave-level segmented shfl reduce
// (batch sorted/monotonic; (lane+o)<64 guard against bpermute mod-64 wrap)
// + per-run-head atomicAdd into pooled; no outs write.
#define AGG_NB 128
#define CSR_CAP 2304
template <bool POOL>
__global__ __launch_bounds__(512) void k_agg(const float* __restrict__ hs,
                                             const float* __restrict__ dinv,
                                             const int* __restrict__ offs,
                                             const int* __restrict__ csr,
                                             const float* __restrict__ bias,
                                             float* __restrict__ outs,
                                             const int* __restrict__ batch,
                                             float* __restrict__ pooled, int n) {
    __shared__ int lofs[AGG_NB + 1];
    __shared__ int lcsr[CSR_CAP];

    int slice = blockIdx.x & 7;
    int chunk = blockIdx.x >> 3;
    int node0 = chunk * AGG_NB;
    int nend = node0 + AGG_NB; if (nend > n) nend = n;
    int nn = nend - node0;
    if ((int)threadIdx.x <= nn) lofs[threadIdx.x] = offs[node0 + threadIdx.x];
    __syncthreads();
    int S = lofs[0];
    int span = lofs[nn] - S;
    bool uselds = (span <= CSR_CAP);
    if (uselds) {
        for (int i = threadIdx.x; i < span; i += 512) lcsr[i] = csr[S + i];
    }
    __syncthreads();

    int lnode = threadIdx.x >> 2;
    int node = node0 + lnode;
    bool act = node < n;
    int l4q = threadIdx.x & 3;
    int l4 = l4q * 4;

    const float* hbase = hs + (size_t)slice * n * 16;
    f32x4 v = (f32x4){0.f, 0.f, 0.f, 0.f};
    if (act) {
        float di = dinv[node];
        int s = lofs[lnode] - S, e = lofs[lnode + 1] - S;
        f32x4 acc = *(const f32x4*)(hbase + (size_t)node * 16 + l4);  // self term
        if (uselds) {
            int p = s;
            for (; p + 8 <= e; p += 8) {
                int r0 = lcsr[p],     r1 = lcsr[p + 1], r2 = lcsr[p + 2], r3 = lcsr[p + 3];
                int r4 = lcsr[p + 4], r5 = lcsr[p + 5], r6 = lcsr[p + 6], r7 = lcsr[p + 7];
                f32x4 h0 = *(const f32x4*)(hbase + (size_t)r0 * 16 + l4);
                f32x4 h1 = *(const f32x4*)(hbase + (size_t)r1 * 16 + l4);
                f32x4 h2 = *(const f32x4*)(hbase + (size_t)r2 * 16 + l4);
                f32x4 h3 = *(const f32x4*)(hbase + (size_t)r3 * 16 + l4);
                f32x4 h4 = *(const f32x4*)(hbase + (size_t)r4 * 16 + l4);
                f32x4 h5 = *(const f32x4*)(hbase + (size_t)r5 * 16 + l4);
                f32x4 h6 = *(const f32x4*)(hbase + (size_t)r6 * 16 + l4);
                f32x4 h7 = *(const f32x4*)(hbase + (size_t)r7 * 16 + l4);
                acc += ((h0 + h1) + (h2 + h3)) + ((h4 + h5) + (h6 + h7));
            }
            for (; p + 4 <= e; p += 4) {
                int r0 = lcsr[p], r1 = lcsr[p + 1], r2 = lcsr[p + 2], r3 = lcsr[p + 3];
                f32x4 h0 = *(const f32x4*)(hbase + (size_t)r0 * 16 + l4);
                f32x4 h1 = *(const f32x4*)(hbase + (size_t)r1 * 16 + l4);
                f32x4 h2 = *(const f32x4*)(hbase + (size_t)r2 * 16 + l4);
                f32x4 h3 = *(const f32x4*)(hbase + (size_t)r3 * 16 + l4);
                acc += (h0 + h1) + (h2 + h3);
            }
            for (; p < e; ++p)
                acc += *(const f32x4*)(hbase + (size_t)lcsr[p] * 16 + l4);
        } else {
            const int* gcsr = csr + S;
            int p = s;
            for (; p + 4 <= e; p += 4) {
                int r0 = gcsr[p], r1 = gcsr[p + 1], r2 = gcsr[p + 2], r3 = gcsr[p + 3];
                f32x4 h0 = *(const f32x4*)(hbase + (size_t)r0 * 16 + l4);
                f32x4 h1 = *(const f32x4*)(hbase + (size_t)r1 * 16 + l4);
                f32x4 h2 = *(const f32x4*)(hbase + (size_t)r2 * 16 + l4);
                f32x4 h3 = *(const f32x4*)(hbase + (size_t)r3 * 16 + l4);
                acc += (h0 + h1) + (h2 + h3);
            }
            for (; p < e; ++p)
                acc += *(const f32x4*)(hbase + (size_t)gcsr[p] * 16 + l4);
        }
        f32x4 b4 = *(const f32x4*)(bias + slice * 16 + l4);
#pragma unroll
        for (int j = 0; j < 4; ++j) v[j] = fmaxf(acc[j] * di + b4[j], 0.f);
    }

    if constexpr (!POOL) {
        if (act)
            __builtin_nontemporal_store(v, (f32x4*)(outs + ((size_t)slice * n + node) * 16 + l4));
    } else {
        // wave-level segmented reduce over 16 nodes/wave (batch sorted ->
        // monotone segment ids; -1 sentinel for inactive tail lanes).
        // (lane+o)<64 guard: CDNA shfl_down wraps mod 64 (ds_bpermute).
        int g = act ? batch[node] : -1;
        int lane = threadIdx.x & 63;
#pragma unroll
        for (int o = 4; o <= 32; o <<= 1) {
            f32x4 ov;
            ov[0] = __shfl_down(v[0], o, 64);
            ov[1] = __shfl_down(v[1], o, 64);
            ov[2] = __shfl_down(v[2], o, 64);
            ov[3] = __shfl_down(v[3], o, 64);
            int og = __shfl_down(g, o, 64);
            if ((lane + o) < 64 && og == g) v += ov;
        }
        int pg = __shfl_up(g, 4, 64);
        if (act && (lane < 4 || pg != g)) {
            float* pp = pooled + (size_t)g * D + slice * 16 + l4;
            atomicAdd(pp + 0, v[0]);
            atomicAdd(pp + 1, v[1]);
            atomicAdd(pp + 2, v[2]);
            atomicAdd(pp + 3, v[3]);
        }
    }
}

// ---------- final: pooled/cnt then @ Wf + bf ----------
__global__ __launch_bounds__(128) void k_final(const float* __restrict__ pooled,
                                               const int* __restrict__ batch, int n,
                                               const float* __restrict__ Wf,
                                               const float* __restrict__ bf,
                                               float* __restrict__ out) {
    __shared__ int sse[2];
    __shared__ float pr[D];
    int g = blockIdx.x;
    if (threadIdx.x == 0) {
        int lo = 0, hi = n;
        while (lo < hi) { int m = (lo + hi) >> 1; if (batch[m] < g) lo = m + 1; else hi = m; }
        sse[0] = lo;
    } else if (threadIdx.x == 64) {
        int lo = 0, hi = n;
        while (lo < hi) { int m = (lo + hi) >> 1; if (batch[m] < g + 1) lo = m + 1; else hi = m; }
        sse[1] = lo;
    }
    __syncthreads();
    float cnt = (float)(sse[1] - sse[0]);
    if (cnt < 1.f) cnt = 1.f;
    int d = threadIdx.x;
    pr[d] = pooled[(size_t)g * D + d] / cnt;
    __syncthreads();
    float o = bf[d];
#pragma unroll 8
    for (int k = 0; k < D; ++k) o += pr[k] * Wf[k * D + d];
    out[g * D + d] = o;
}

extern "C" void kernel_launch(void* const* d_in, const int* in_sizes, int n_in,
                              void* d_out, int out_size, void* d_ws, size_t ws_size,
                              hipStream_t stream) {
    const float* x  = (const float*)d_in[0];
    const int*   ei = (const int*)d_in[1];
    const int*   bt = (const int*)d_in[2];
    const float* W1 = (const float*)d_in[3];
    const float* b1 = (const float*)d_in[4];
    const float* W2 = (const float*)d_in[5];
    const float* b2 = (const float*)d_in[6];
    const float* Wf = (const float*)d_in[7];
    const float* bf = (const float*)d_in[8];
    float* out = (float*)d_out;

    int n = in_sizes[2];
    int E = in_sizes[1] / 2;
    int G = out_size / D;

    char* w = (char*)d_ws;
    size_t off = 0;
    auto alloc = [&](size_t bytes) -> void* {
        void* p = w + off;
        off = (off + bytes + 511) & ~(size_t)511;
        return p;
    };
    int*    degcnt = (int*)alloc((size_t)n * 4);
    int*    cursor = (int*)alloc((size_t)n * 4);
    int*    offs   = (int*)alloc((size_t)(n + 1) * 4);
    float*  dinv   = (float*)alloc((size_t)n * 4);
    int*    csr    = (int*)alloc((size_t)E * 4);
    float*  hw     = (float*)alloc((size_t)n * D * 4);   // slice-major [8][n][16]
    float*  ha     = (float*)alloc((size_t)n * D * 4);   // slice-major [8][n][16]
    float*  pooled = (float*)alloc((size_t)G * D * 4);
    int*    partial= (int*)alloc((size_t)256 * 4);
    ushort* wt1h   = (ushort*)alloc((size_t)D * D * 2);
    ushort* wt1l   = (ushort*)alloc((size_t)D * D * 2);
    ushort* wt2h   = (ushort*)alloc((size_t)D * D * 2);
    ushort* wt2l   = (ushort*)alloc((size_t)D * D * 2);

    int n4 = (n + 3) / 4;
    int zb = (n4 + 255) / 256;
    int p4 = (G * D + 3) / 4;
    int pb = (p4 + 255) / 256;
    k_init<<<zb + pb + 16, 256, 0, stream>>>((int4*)degcnt, n4, zb,
                                             (int4*)pooled, p4, pb,
                                             W1, W2, wt1h, wt1l, wt2h, wt2l);

    int e4b = (E / 4 + 255) / 256 + 1;
    int sb = (n + 1023) / 1024;
    k_deg<<<e4b, 256, 0, stream>>>(ei + E, degcnt, E);
    k_scan_partial<<<sb, 256, 0, stream>>>(degcnt, partial, n);
    k_scan_final<<<sb, 256, 0, stream>>>(degcnt, partial, offs, cursor, dinv, n, E);
    k_fill<<<e4b, 256, 0, stream>>>(ei, cursor, csr, E);

    int gb = (n + TM - 1) / TM;
    int ab = 8 * ((n + AGG_NB - 1) / AGG_NB);
    size_t lds_bytes = 64 * 1024;

    k_gemm<false><<<gb, 512, lds_bytes, stream>>>(x, wt1h, wt1l, dinv, hw, n);
    k_agg<false><<<ab, 512, 0, stream>>>(hw, dinv, offs, csr, b1, ha, bt, nullptr, n);
    k_gemm<true><<<gb, 512, lds_bytes, stream>>>(ha, wt2h, wt2l, dinv, hw, n);
    k_agg<true><<<ab, 512, 0, stream>>>(hw, dinv, offs, csr, b2, nullptr, bt, pooled, n);
    k_final<<<G, 128, 0, stream>>>(pooled, bt, n, Wf, bf, out);
}